// Round 1
// baseline (3447.926 us; speedup 1.0000x reference)
//
#include <hip/hip_runtime.h>

// L2BoundedLTICell: B=32, T=4096, d=128.
// v-space trick: v = x @ S^T  =>  v' = v K11^T + u K12^T ; y = v K21^T + u K22^T ; x = v Sinv^T.
// Chunked scan: L=16, 256 chunks/batch, 8192 rows.

#define B_   32
#define T_   4096
#define D_   128
#define LCH  16
#define NCH  256

// ---- ws layout (floats) ----
#define O_MSQ0    0LL
#define O_MSQ1    65536LL
#define O_PART    131072LL          // 16*8
#define O_Z0      131200LL
#define O_Z1      147584LL
#define O_TN      163968LL
#define O_WA      180352LL
#define O_WB      196736LL
#define O_WC      213120LL
#define O_WD      229504LL
#define O_SINVT   245888LL
#define O_V0      262272LL
#define O_PW      266368LL          // 8 slots * 16384  (P2,P4,P8,P16,P32,P64,P128,P256)
#define O_CONTRIB 397440LL          // 8192*128
#define O_SC      1446016LL         // 32*16*128
#define O_SSUP    1511552LL
#define O_SCHUNK  1577088LL         // 8192*128
#define WS_FLOATS 2625664LL

// ================= sigma chain =================
// M0 = N^T N  (N = K_raw, 256x256), plus trace partials of M0.
__global__ void k_m0(const float* __restrict__ N, float* __restrict__ M0, float* __restrict__ part) {
  __shared__ float TA[32][36], TB[32][36], dbuf[32];
  const int t  = threadIdx.x;
  const int ab = blockIdx.x >> 3, bb = blockIdx.x & 7;
  const int a0 = ab * 32, b0 = bb * 32;
  const int ar = t >> 3, c4 = (t & 7) << 2;
  float s0 = 0.f, s1 = 0.f, s2 = 0.f, s3 = 0.f;
  for (int r0 = 0; r0 < 256; r0 += 32) {
    const int rr = t >> 3, cc = (t & 7) << 2;
    *(float4*)&TA[rr][cc] = *(const float4*)&N[(r0 + rr) * 256 + a0 + cc];
    *(float4*)&TB[rr][cc] = *(const float4*)&N[(r0 + rr) * 256 + b0 + cc];
    __syncthreads();
#pragma unroll 8
    for (int r = 0; r < 32; r++) {
      const float av = TA[r][ar];
      const float4 bv = *(const float4*)&TB[r][c4];
      s0 += av * bv.x; s1 += av * bv.y; s2 += av * bv.z; s3 += av * bv.w;
    }
    __syncthreads();
  }
  float4 o; o.x = s0; o.y = s1; o.z = s2; o.w = s3;
  *(float4*)&M0[(a0 + ar) * 256 + b0 + c4] = o;
  if (ab == bb) {
    const int d = ar - c4;
    if (d >= 0 && d < 4) dbuf[ar] = (d == 0) ? s0 : (d == 1) ? s1 : (d == 2) ? s2 : s3;
    __syncthreads();
    if (t == 0) { float s = 0.f; for (int i = 0; i < 32; i++) s += dbuf[i]; part[ab] = s; }
  }
}

// Y = (X/c)^2 where c = sum(pIn[0..7]);  pOut gets trace partials of Y.
__global__ void k_sq(const float* __restrict__ X, float* __restrict__ Y,
                     const float* __restrict__ pIn, float* __restrict__ pOut) {
  __shared__ float TA[32][36], TB[32][36], dbuf[32];
  float c = 0.f;
#pragma unroll
  for (int i = 0; i < 8; i++) c += pIn[i];
  const float ic2 = 1.0f / (c * c);
  const int t  = threadIdx.x;
  const int ab = blockIdx.x >> 3, bb = blockIdx.x & 7;
  const int a0 = ab * 32, b0 = bb * 32;
  const int ar = t >> 3, c4 = (t & 7) << 2;
  float s0 = 0.f, s1 = 0.f, s2 = 0.f, s3 = 0.f;
  for (int m0 = 0; m0 < 256; m0 += 32) {
    const int rr = t >> 3, cc = (t & 7) << 2;
    *(float4*)&TA[rr][cc] = *(const float4*)&X[(a0 + rr) * 256 + m0 + cc];
    *(float4*)&TB[rr][cc] = *(const float4*)&X[(m0 + rr) * 256 + b0 + cc];
    __syncthreads();
#pragma unroll 8
    for (int m = 0; m < 32; m++) {
      const float av = TA[ar][m];
      const float4 bv = *(const float4*)&TB[m][c4];
      s0 += av * bv.x; s1 += av * bv.y; s2 += av * bv.z; s3 += av * bv.w;
    }
    __syncthreads();
  }
  s0 *= ic2; s1 *= ic2; s2 *= ic2; s3 *= ic2;
  float4 o; o.x = s0; o.y = s1; o.z = s2; o.w = s3;
  *(float4*)&Y[(a0 + ar) * 256 + b0 + c4] = o;
  if (ab == bb) {
    const int d = ar - c4;
    if (d >= 0 && d < 4) dbuf[ar] = (d == 0) ? s0 : (d == 1) ? s1 : (d == 2) ? s2 : s3;
    __syncthreads();
    if (t == 0) { float s = 0.f; for (int i = 0; i < 32; i++) s += dbuf[i]; pOut[ab] = s; }
  }
}

// ================= Sinv: register GJ (unpivoted) =================
__global__ void k_gj(const float* __restrict__ S, float* __restrict__ Z) {
  __shared__ float LCol[128];
  const int c = threadIdx.x;
  float4 a4[32];
  if (c < 128) {
#pragma unroll
    for (int q = 0; q < 32; q++) {
      a4[q].x = S[(4 * q + 0) * 128 + c]; a4[q].y = S[(4 * q + 1) * 128 + c];
      a4[q].z = S[(4 * q + 2) * 128 + c]; a4[q].w = S[(4 * q + 3) * 128 + c];
    }
  } else {
    const int d = c - 128;
#pragma unroll
    for (int q = 0; q < 32; q++) {
      a4[q].x = (d == 4 * q + 0) ? 1.f : 0.f; a4[q].y = (d == 4 * q + 1) ? 1.f : 0.f;
      a4[q].z = (d == 4 * q + 2) ? 1.f : 0.f; a4[q].w = (d == 4 * q + 3) ? 1.f : 0.f;
    }
  }
  for (int p = 0; p < 128; p++) {
    if (c == p) {
#pragma unroll
      for (int q = 0; q < 32; q++) *(float4*)&LCol[4 * q] = a4[q];
    }
    __syncthreads();
    float4 sq = a4[0];
#pragma unroll
    for (int q = 1; q < 32; q++) if ((p >> 2) == q) sq = a4[q];
    const int pm = p & 3;
    const float ap = pm == 0 ? sq.x : pm == 1 ? sq.y : pm == 2 ? sq.z : sq.w;
    const float aps = ap / LCol[p];
#pragma unroll
    for (int q = 0; q < 32; q++) {
      const float4 L = *(const float4*)&LCol[4 * q];
      float4 v = a4[q];
      v.x = (4 * q + 0 == p) ? aps : v.x - L.x * aps;
      v.y = (4 * q + 1 == p) ? aps : v.y - L.y * aps;
      v.z = (4 * q + 2 == p) ? aps : v.z - L.z * aps;
      v.w = (4 * q + 3 == p) ? aps : v.w - L.w * aps;
      a4[q] = v;
    }
    __syncthreads();
  }
  if (c >= 128) {
    const int cc = c - 128;
#pragma unroll
    for (int q = 0; q < 32; q++) {
      Z[(4 * q + 0) * 128 + cc] = a4[q].x; Z[(4 * q + 1) * 128 + cc] = a4[q].y;
      Z[(4 * q + 2) * 128 + cc] = a4[q].z; Z[(4 * q + 3) * 128 + cc] = a4[q].w;
    }
  }
}

// ================= generic 128x128 GEMM: Dst = A@B  (mode1: Dst = 2C - A@B) =================
__global__ void k_mm(const float* __restrict__ A, const float* __restrict__ Bm,
                     float* __restrict__ Dst, const float* __restrict__ C, int mode) {
  __shared__ float TA[32][36], TB[32][36];
  const int t  = threadIdx.x;
  const int ab = blockIdx.x >> 2, bb = blockIdx.x & 3;
  const int a0 = ab * 32, b0 = bb * 32;
  const int ar = t >> 3, c4 = (t & 7) << 2;
  float s0 = 0.f, s1 = 0.f, s2 = 0.f, s3 = 0.f;
  for (int m0 = 0; m0 < 128; m0 += 32) {
    const int rr = t >> 3, cc = (t & 7) << 2;
    *(float4*)&TA[rr][cc] = *(const float4*)&A[(a0 + rr) * 128 + m0 + cc];
    *(float4*)&TB[rr][cc] = *(const float4*)&Bm[(m0 + rr) * 128 + b0 + cc];
    __syncthreads();
#pragma unroll 8
    for (int m = 0; m < 32; m++) {
      const float av = TA[ar][m];
      const float4 bv = *(const float4*)&TB[m][c4];
      s0 += av * bv.x; s1 += av * bv.y; s2 += av * bv.z; s3 += av * bv.w;
    }
    __syncthreads();
  }
  const int oi = (a0 + ar) * 128 + b0 + c4;
  if (mode == 1) {
    s0 = 2.f * C[oi + 0] - s0; s1 = 2.f * C[oi + 1] - s1;
    s2 = 2.f * C[oi + 2] - s2; s3 = 2.f * C[oi + 3] - s3;
  }
  float4 o; o.x = s0; o.y = s1; o.z = s2; o.w = s3;
  *(float4*)&Dst[oi] = o;
}

// ================= build operators =================
__global__ void k_ops(const float* __restrict__ Kraw, const float* __restrict__ S,
                      const float* __restrict__ x0, const float* __restrict__ part,
                      const float* __restrict__ Z, float* __restrict__ WA, float* __restrict__ WB,
                      float* __restrict__ WC, float* __restrict__ WD,
                      float* __restrict__ SinvT, float* __restrict__ v0) {
  // sigma from trace chain: log2 l1 = sum_j 2^-j log2 c_j
  double logl = 0.0, w = 1.0;
  for (int k = 0; k <= 10; k++) {
    double c = 0.0;
    for (int i = 0; i < 8; i++) c += (double)part[k * 8 + i];
    logl += w * log2(c); w *= 0.5;
  }
  double sigma = exp2(0.5 * logl);
  if (sigma < 1e-5) sigma = 1e-5;
  const float invs = (float)(1.0 / (sigma + 0.002));
  const int wg = blockIdx.x, t = threadIdx.x;
  if (wg < 4) {
    float* dst = wg == 0 ? WA : wg == 1 ? WB : wg == 2 ? WC : WD;
    const int ro = (wg >> 1) * 128, co = (wg & 1) * 128;
    for (int e = t; e < 16384; e += 256) {
      const int i = e >> 7, o = e & 127;
      dst[e] = Kraw[(ro + o) * 256 + co + i] * invs;   // dst[i][o] = Kblk[o][i]/s
    }
  } else if (wg == 4) {
    for (int e = t; e < 16384; e += 256) {
      const int i = e >> 7, o = e & 127;
      SinvT[e] = Z[o * 128 + i];
    }
  } else {
    for (int e = t; e < 4096; e += 256) {
      const int b = e >> 7, o = e & 127;
      float s = 0.f;
      for (int i = 0; i < 128; i++) s += x0[b * 128 + i] * S[o * 128 + i];
      v0[e] = s;   // v0 = x0 @ S^T
    }
  }
}

// ================= chunk scan (the big kernel) =================
// MODE 0: zero-init, write final state to contrib.  MODE 1: init from initp, store v_t to outv.
template <int MODE>
__global__ __launch_bounds__(256) void k_scan(const float* __restrict__ u,
                                              const float* __restrict__ WAg,
                                              const float* __restrict__ WBg,
                                              const float* __restrict__ initp,
                                              float* __restrict__ outv,
                                              float* __restrict__ contribp) {
  extern __shared__ float lds[];
  float* WAl  = lds;            // 128*128
  float* WBuf = lds + 16384;    // 64*128
  float* XU   = lds + 24576;    // 256*36  [i][r], r = row in wg (32)
  const int t   = threadIdx.x;
  const int w   = blockIdx.x;          // 0..255
  const int gr0 = w * 32;
  const int b   = gr0 >> 8;
  const int c0  = gr0 & 255;
  // load WA (persistent)
  for (int e = t * 4; e < 16384; e += 1024)
    *(float4*)&WAl[e] = *(const float4*)&WAg[e];
  // init v-half of XU
  for (int e = t * 4; e < 4096; e += 1024) {
    const int r = e >> 7, i = e & 127;
    if (MODE == 1) {
      const float4 a = *(const float4*)&initp[((gr0 + r) << 7) + i];
      XU[(i + 0) * 36 + r] = a.x; XU[(i + 1) * 36 + r] = a.y;
      XU[(i + 2) * 36 + r] = a.z; XU[(i + 3) * 36 + r] = a.w;
    } else {
      XU[(i + 0) * 36 + r] = 0.f; XU[(i + 1) * 36 + r] = 0.f;
      XU[(i + 2) * 36 + r] = 0.f; XU[(i + 3) * 36 + r] = 0.f;
    }
  }
  __syncthreads();
  const int rt = t >> 5, ot = t & 31;
  const int r0 = rt * 4, o0 = ot * 4;
  for (int j = 0; j < LCH; j++) {
    // store current v (pre-step state) and stage u_t
    for (int e = t * 4; e < 4096; e += 1024) {
      const int r = e >> 7, i = e & 127;
      const int gidx = (((b << 12) + (c0 + r) * LCH + j) << 7) + i;
      if (MODE == 1) {
        float4 a;
        a.x = XU[(i + 0) * 36 + r]; a.y = XU[(i + 1) * 36 + r];
        a.z = XU[(i + 2) * 36 + r]; a.w = XU[(i + 3) * 36 + r];
        *(float4*)&outv[gidx] = a;
      }
      const float4 uv = *(const float4*)&u[gidx];
      XU[(128 + i + 0) * 36 + r] = uv.x; XU[(128 + i + 1) * 36 + r] = uv.y;
      XU[(128 + i + 2) * 36 + r] = uv.z; XU[(128 + i + 3) * 36 + r] = uv.w;
    }
    __syncthreads();   // A
    float a00 = 0, a01 = 0, a02 = 0, a03 = 0, a10 = 0, a11 = 0, a12 = 0, a13 = 0;
    float a20 = 0, a21 = 0, a22 = 0, a23 = 0, a30 = 0, a31 = 0, a32 = 0, a33 = 0;
#pragma unroll 4
    for (int i = 0; i < 128; i++) {
      const float4 xv = *(const float4*)&XU[i * 36 + r0];
      const float4 wv = *(const float4*)&WAl[(i << 7) + o0];
      a00 += xv.x * wv.x; a01 += xv.x * wv.y; a02 += xv.x * wv.z; a03 += xv.x * wv.w;
      a10 += xv.y * wv.x; a11 += xv.y * wv.y; a12 += xv.y * wv.z; a13 += xv.y * wv.w;
      a20 += xv.z * wv.x; a21 += xv.z * wv.y; a22 += xv.z * wv.z; a23 += xv.z * wv.w;
      a30 += xv.w * wv.x; a31 += xv.w * wv.y; a32 += xv.w * wv.z; a33 += xv.w * wv.w;
    }
    // u-half in two WB chunks
    for (int half = 0; half < 2; half++) {
      for (int e = t * 4; e < 8192; e += 1024)
        *(float4*)&WBuf[e] = *(const float4*)&WBg[half * 8192 + e];
      __syncthreads();  // C / E
      const int ibase = 128 + half * 64;
#pragma unroll 4
      for (int i = 0; i < 64; i++) {
        const float4 xv = *(const float4*)&XU[(ibase + i) * 36 + r0];
        const float4 wv = *(const float4*)&WBuf[(i << 7) + o0];
        a00 += xv.x * wv.x; a01 += xv.x * wv.y; a02 += xv.x * wv.z; a03 += xv.x * wv.w;
        a10 += xv.y * wv.x; a11 += xv.y * wv.y; a12 += xv.y * wv.z; a13 += xv.y * wv.w;
        a20 += xv.z * wv.x; a21 += xv.z * wv.y; a22 += xv.z * wv.z; a23 += xv.z * wv.w;
        a30 += xv.w * wv.x; a31 += xv.w * wv.y; a32 += xv.w * wv.z; a33 += xv.w * wv.w;
      }
      if (half == 0) __syncthreads();  // D (before restage)
    }
    // writeback new v into XU v-half (all threads past C => v-reads done)
    XU[(o0 + 0) * 36 + r0 + 0] = a00; XU[(o0 + 1) * 36 + r0 + 0] = a01;
    XU[(o0 + 2) * 36 + r0 + 0] = a02; XU[(o0 + 3) * 36 + r0 + 0] = a03;
    XU[(o0 + 0) * 36 + r0 + 1] = a10; XU[(o0 + 1) * 36 + r0 + 1] = a11;
    XU[(o0 + 2) * 36 + r0 + 1] = a12; XU[(o0 + 3) * 36 + r0 + 1] = a13;
    XU[(o0 + 0) * 36 + r0 + 2] = a20; XU[(o0 + 1) * 36 + r0 + 2] = a21;
    XU[(o0 + 2) * 36 + r0 + 2] = a22; XU[(o0 + 3) * 36 + r0 + 2] = a23;
    XU[(o0 + 0) * 36 + r0 + 3] = a30; XU[(o0 + 1) * 36 + r0 + 3] = a31;
    XU[(o0 + 2) * 36 + r0 + 3] = a32; XU[(o0 + 3) * 36 + r0 + 3] = a33;
    __syncthreads();  // F
  }
  if (MODE == 0) {
    for (int e = t * 4; e < 4096; e += 1024) {
      const int r = e >> 7, i = e & 127;
      float4 a;
      a.x = XU[(i + 0) * 36 + r]; a.y = XU[(i + 1) * 36 + r];
      a.z = XU[(i + 2) * 36 + r]; a.w = XU[(i + 3) * 36 + r];
      *(float4*)&contribp[((gr0 + r) << 7) + i] = a;
    }
  }
}

// ================= phase-2 combine (matvec scans over chunks) =================
// mode0: sc[b][g]   = scan16(0, contrib, P16)
// mode1: Ssup[b][g] = states of super-scan(v0, sc, P256), stored pre-update
// mode2: schunk     = states of scan16(Ssup[b][g], contrib, P16), stored pre-update
__global__ void k_comb(const float* __restrict__ P, const float* __restrict__ initv,
                       const float* __restrict__ add, float* __restrict__ st,
                       float* __restrict__ fin, int mode) {
  extern __shared__ float lds[];
  float* Pl = lds;            // 128*132
  float* tc = lds + 16896;    // 128
  float* pb = lds + 17024;    // 256
  const int blk = blockIdx.x, t = threadIdx.x;
  const int o = t & 127, h = t >> 7;
  int addBase = 0, stBase = 0, iIdx = 0, fIdx = 0;
  if (mode == 0) { const int bb = blk >> 4, gg = blk & 15; addBase = bb * 256 + gg * 16; fIdx = bb * 16 + gg; }
  else if (mode == 1) { const int bb = blk; addBase = bb * 16; stBase = bb * 16; iIdx = bb; }
  else { const int bb = blk >> 4, gg = blk & 15; addBase = bb * 256 + gg * 16; stBase = addBase; iIdx = bb * 16 + gg; }
  for (int e = t * 4; e < 16384; e += 1024) {
    const int i = e >> 7, oo = e & 127;
    *(float4*)&Pl[i * 132 + oo] = *(const float4*)&P[e];
  }
  if (h == 0) tc[o] = (mode == 0) ? 0.f : initv[iIdx * 128 + o];
  __syncthreads();
  for (int k = 0; k < 16; k++) {
    float s = 0.f;
#pragma unroll 8
    for (int i = 0; i < 64; i++) {
      const int ii = h * 64 + i;
      s += tc[ii] * Pl[ii * 132 + o];
    }
    pb[h * 128 + o] = s;
    __syncthreads();
    if (h == 0) {
      if (mode != 0) st[(stBase + k) * 128 + o] = tc[o];
      tc[o] = pb[o] + pb[128 + o] + add[(addBase + k) * 128 + o];
    }
    __syncthreads();
  }
  if (mode == 0 && h == 0) fin[fIdx * 128 + o] = tc[o];
}

// ================= Y = V@WC + U@WD =================
__global__ __launch_bounds__(256) void k_phy(const float* __restrict__ v, const float* __restrict__ u,
                                             const float* __restrict__ WCg, const float* __restrict__ WDg,
                                             float* __restrict__ y) {
  extern __shared__ float lds[];
  float* Wl = lds;            // 128*132
  float* VT = lds + 16896;    // 128*68
  const int t = threadIdx.x;
  const int m0 = blockIdx.x * 64;
  const int rt = t >> 4, ot = t & 15;
  const int r0 = rt * 4, o0 = ot * 8;
  float4 accl[4], acch[4];
#pragma unroll
  for (int rr = 0; rr < 4; rr++) { accl[rr].x = accl[rr].y = accl[rr].z = accl[rr].w = 0.f;
                                   acch[rr].x = acch[rr].y = acch[rr].z = acch[rr].w = 0.f; }
  for (int pass = 0; pass < 2; pass++) {
    const float* W = pass ? WDg : WCg;
    const float* A = pass ? u : v;
    for (int e = t * 4; e < 16384; e += 1024) {
      const int i = e >> 7, oo = e & 127;
      *(float4*)&Wl[i * 132 + oo] = *(const float4*)&W[e];
    }
    for (int e = t * 4; e < 8192; e += 1024) {
      const int r = e >> 7, i = e & 127;
      const float4 a = *(const float4*)&A[((m0 + r) << 7) + i];
      VT[(i + 0) * 68 + r] = a.x; VT[(i + 1) * 68 + r] = a.y;
      VT[(i + 2) * 68 + r] = a.z; VT[(i + 3) * 68 + r] = a.w;
    }
    __syncthreads();
#pragma unroll 2
    for (int i = 0; i < 128; i++) {
      const float4 xv = *(const float4*)&VT[i * 68 + r0];
      const float4 w0 = *(const float4*)&Wl[i * 132 + o0];
      const float4 w1 = *(const float4*)&Wl[i * 132 + o0 + 4];
      const float xs0 = xv.x, xs1 = xv.y, xs2 = xv.z, xs3 = xv.w;
      accl[0].x += xs0 * w0.x; accl[0].y += xs0 * w0.y; accl[0].z += xs0 * w0.z; accl[0].w += xs0 * w0.w;
      acch[0].x += xs0 * w1.x; acch[0].y += xs0 * w1.y; acch[0].z += xs0 * w1.z; acch[0].w += xs0 * w1.w;
      accl[1].x += xs1 * w0.x; accl[1].y += xs1 * w0.y; accl[1].z += xs1 * w0.z; accl[1].w += xs1 * w0.w;
      acch[1].x += xs1 * w1.x; acch[1].y += xs1 * w1.y; acch[1].z += xs1 * w1.z; acch[1].w += xs1 * w1.w;
      accl[2].x += xs2 * w0.x; accl[2].y += xs2 * w0.y; accl[2].z += xs2 * w0.z; accl[2].w += xs2 * w0.w;
      acch[2].x += xs2 * w1.x; acch[2].y += xs2 * w1.y; acch[2].z += xs2 * w1.z; acch[2].w += xs2 * w1.w;
      accl[3].x += xs3 * w0.x; accl[3].y += xs3 * w0.y; accl[3].z += xs3 * w0.z; accl[3].w += xs3 * w0.w;
      acch[3].x += xs3 * w1.x; acch[3].y += xs3 * w1.y; acch[3].z += xs3 * w1.z; acch[3].w += xs3 * w1.w;
    }
    __syncthreads();
  }
#pragma unroll
  for (int rr = 0; rr < 4; rr++) {
    *(float4*)&y[((m0 + r0 + rr) << 7) + o0] = accl[rr];
    *(float4*)&y[((m0 + r0 + rr) << 7) + o0 + 4] = acch[rr];
  }
}

// ================= X = V @ SinvT  (in place on vx) =================
__global__ __launch_bounds__(256) void k_phx(float* __restrict__ vx, const float* __restrict__ Wg) {
  extern __shared__ float lds[];
  float* Wl = lds;
  float* VT = lds + 16896;
  const int t = threadIdx.x;
  const int m0 = blockIdx.x * 64;
  const int rt = t >> 4, ot = t & 15;
  const int r0 = rt * 4, o0 = ot * 8;
  float4 accl[4], acch[4];
#pragma unroll
  for (int rr = 0; rr < 4; rr++) { accl[rr].x = accl[rr].y = accl[rr].z = accl[rr].w = 0.f;
                                   acch[rr].x = acch[rr].y = acch[rr].z = acch[rr].w = 0.f; }
  for (int e = t * 4; e < 16384; e += 1024) {
    const int i = e >> 7, oo = e & 127;
    *(float4*)&Wl[i * 132 + oo] = *(const float4*)&Wg[e];
  }
  for (int e = t * 4; e < 8192; e += 1024) {
    const int r = e >> 7, i = e & 127;
    const float4 a = *(const float4*)&vx[((m0 + r) << 7) + i];
    VT[(i + 0) * 68 + r] = a.x; VT[(i + 1) * 68 + r] = a.y;
    VT[(i + 2) * 68 + r] = a.z; VT[(i + 3) * 68 + r] = a.w;
  }
  __syncthreads();
#pragma unroll 2
  for (int i = 0; i < 128; i++) {
    const float4 xv = *(const float4*)&VT[i * 68 + r0];
    const float4 w0 = *(const float4*)&Wl[i * 132 + o0];
    const float4 w1 = *(const float4*)&Wl[i * 132 + o0 + 4];
    const float xs0 = xv.x, xs1 = xv.y, xs2 = xv.z, xs3 = xv.w;
    accl[0].x += xs0 * w0.x; accl[0].y += xs0 * w0.y; accl[0].z += xs0 * w0.z; accl[0].w += xs0 * w0.w;
    acch[0].x += xs0 * w1.x; acch[0].y += xs0 * w1.y; acch[0].z += xs0 * w1.z; acch[0].w += xs0 * w1.w;
    accl[1].x += xs1 * w0.x; accl[1].y += xs1 * w0.y; accl[1].z += xs1 * w0.z; accl[1].w += xs1 * w0.w;
    acch[1].x += xs1 * w1.x; acch[1].y += xs1 * w1.y; acch[1].z += xs1 * w1.z; acch[1].w += xs1 * w1.w;
    accl[2].x += xs2 * w0.x; accl[2].y += xs2 * w0.y; accl[2].z += xs2 * w0.z; accl[2].w += xs2 * w0.w;
    acch[2].x += xs2 * w1.x; acch[2].y += xs2 * w1.y; acch[2].z += xs2 * w1.z; acch[2].w += xs2 * w1.w;
    accl[3].x += xs3 * w0.x; accl[3].y += xs3 * w0.y; accl[3].z += xs3 * w0.z; accl[3].w += xs3 * w0.w;
    acch[3].x += xs3 * w1.x; acch[3].y += xs3 * w1.y; acch[3].z += xs3 * w1.z; acch[3].w += xs3 * w1.w;
  }
#pragma unroll
  for (int rr = 0; rr < 4; rr++) {
    *(float4*)&vx[((m0 + r0 + rr) << 7) + o0] = accl[rr];
    *(float4*)&vx[((m0 + r0 + rr) << 7) + o0 + 4] = acch[rr];
  }
}

// ================= host =================
extern "C" void kernel_launch(void* const* d_in, const int* in_sizes, int n_in,
                              void* d_out, int out_size, void* d_ws, size_t ws_size,
                              hipStream_t stream) {
  (void)in_sizes; (void)n_in; (void)out_size;
  const float* u    = (const float*)d_in[0];
  const float* x0   = (const float*)d_in[1];
  const float* S    = (const float*)d_in[2];
  const float* Kraw = (const float*)d_in[3];
  float* out = (float*)d_out;
  float* yout = out;                       // y_seq: 32*4096*128
  float* vx   = out + 16777216LL;          // x_seq region; holds v_seq until k_phx
  float* ws = (float*)d_ws;
  if (ws_size < (size_t)(WS_FLOATS * 4)) return;

  float* MSQ0 = ws + O_MSQ0;  float* MSQ1 = ws + O_MSQ1;  float* PART = ws + O_PART;
  float* Z0 = ws + O_Z0;      float* Z1 = ws + O_Z1;      float* TN = ws + O_TN;
  float* WA = ws + O_WA;      float* WB = ws + O_WB;      float* WC = ws + O_WC;
  float* WD = ws + O_WD;      float* SINVT = ws + O_SINVT; float* V0 = ws + O_V0;
  float* PW = ws + O_PW;
  float* CONTRIB = ws + O_CONTRIB;  float* SC = ws + O_SC;
  float* SSUP = ws + O_SSUP;        float* SCHUNK = ws + O_SCHUNK;

  // sigma trace chain
  k_m0<<<64, 256, 0, stream>>>(Kraw, MSQ0, PART);
  float* mb[2] = {MSQ0, MSQ1};
  for (int k = 1; k <= 10; k++)
    k_sq<<<64, 256, 0, stream>>>(mb[(k + 1) & 1], mb[k & 1], PART + (k - 1) * 8, PART + k * 8);

  // Sinv: GJ + 3x Newton-Schulz
  k_gj<<<1, 256, 0, stream>>>(S, Z0);
  k_mm<<<16, 256, 0, stream>>>(S, Z0, TN, nullptr, 0);
  k_mm<<<16, 256, 0, stream>>>(Z0, TN, Z1, Z0, 1);
  k_mm<<<16, 256, 0, stream>>>(S, Z1, TN, nullptr, 0);
  k_mm<<<16, 256, 0, stream>>>(Z1, TN, Z0, Z1, 1);
  k_mm<<<16, 256, 0, stream>>>(S, Z0, TN, nullptr, 0);
  k_mm<<<16, 256, 0, stream>>>(Z0, TN, Z1, Z0, 1);

  // operators (scaled transposed K blocks), SinvT, v0
  k_ops<<<6, 256, 0, stream>>>(Kraw, S, x0, PART, Z1, WA, WB, WC, WD, SINVT, V0);

  // powers of WA: P2..P256
  k_mm<<<16, 256, 0, stream>>>(WA, WA, PW + 0, nullptr, 0);
  k_mm<<<16, 256, 0, stream>>>(PW + 0, PW + 0, PW + 16384, nullptr, 0);
  k_mm<<<16, 256, 0, stream>>>(PW + 16384, PW + 16384, PW + 32768, nullptr, 0);
  k_mm<<<16, 256, 0, stream>>>(PW + 32768, PW + 32768, PW + 49152, nullptr, 0);   // P16
  k_mm<<<16, 256, 0, stream>>>(PW + 49152, PW + 49152, PW + 65536, nullptr, 0);
  k_mm<<<16, 256, 0, stream>>>(PW + 65536, PW + 65536, PW + 81920, nullptr, 0);
  k_mm<<<16, 256, 0, stream>>>(PW + 81920, PW + 81920, PW + 98304, nullptr, 0);
  k_mm<<<16, 256, 0, stream>>>(PW + 98304, PW + 98304, PW + 114688, nullptr, 0);  // P256
  float* P16 = PW + 49152;
  float* P256 = PW + 114688;

  const size_t scanLds = 135168;   // (16384 + 8192 + 256*36) * 4
  const size_t combLds = 69120;    // 17280 * 4
  const size_t gemmLds = 102400;   // (16896 + 8704) * 4

  // pass 1: chunk contributions
  k_scan<0><<<256, 256, scanLds, stream>>>(u, WA, WB, nullptr, nullptr, CONTRIB);
  // phase 2: hierarchical combine -> chunk-start states
  k_comb<<<512, 256, combLds, stream>>>(P16, nullptr, CONTRIB, nullptr, SC, 0);
  k_comb<<<32, 256, combLds, stream>>>(P256, V0, SC, SSUP, nullptr, 1);
  k_comb<<<512, 256, combLds, stream>>>(P16, SSUP, CONTRIB, SCHUNK, nullptr, 2);
  // pass 2: true states, stored to out (v-space)
  k_scan<1><<<256, 256, scanLds, stream>>>(u, WA, WB, SCHUNK, vx, nullptr);
  // outputs
  k_phy<<<2048, 256, gemmLds, stream>>>(vx, u, WC, WD, yout);
  k_phx<<<2048, 256, gemmLds, stream>>>(vx, SINVT);
}

// Round 2
// 1425.643 us; speedup vs baseline: 2.4185x; 2.4185x over previous
//
#include <hip/hip_runtime.h>

// L2BoundedLTICell: B=32, T=4096, d=128.
// v-space trick: v = x @ S^T  =>  v' = v K11^T + u K12^T ; y = v K21^T + u K22^T ; x = v Sinv^T.
// Chunked scan: L=16, 256 chunks/batch, 8192 rows.

#define B_   32
#define T_   4096
#define D_   128
#define LCH  16
#define NCH  256

// ---- ws layout (floats) ----
#define O_MSQ0    0LL
#define O_MSQ1    65536LL
#define O_PART    131072LL          // 16*8
#define O_Z0      131200LL
#define O_Z1      147584LL
#define O_TN      163968LL
#define O_WA      180352LL
#define O_WB      196736LL
#define O_WC      213120LL
#define O_WD      229504LL
#define O_SINVT   245888LL
#define O_V0      262272LL
#define O_PW      266368LL          // 8 slots * 16384  (P2,P4,P8,P16,P32,P64,P128,P256)
#define O_CONTRIB 397440LL          // 8192*128
#define O_SC      1446016LL         // 32*16*128
#define O_SSUP    1511552LL
#define O_SCHUNK  1577088LL         // 8192*128
#define WS_FLOATS 2625664LL

// ================= sigma chain =================
// M0 = N^T N  (N = K_raw, 256x256), plus trace partials of M0.
__global__ void k_m0(const float* __restrict__ N, float* __restrict__ M0, float* __restrict__ part) {
  __shared__ float TA[32][36], TB[32][36], dbuf[32];
  const int t  = threadIdx.x;
  const int ab = blockIdx.x >> 3, bb = blockIdx.x & 7;
  const int a0 = ab * 32, b0 = bb * 32;
  const int ar = t >> 3, c4 = (t & 7) << 2;
  float s0 = 0.f, s1 = 0.f, s2 = 0.f, s3 = 0.f;
  for (int r0 = 0; r0 < 256; r0 += 32) {
    const int rr = t >> 3, cc = (t & 7) << 2;
    *(float4*)&TA[rr][cc] = *(const float4*)&N[(r0 + rr) * 256 + a0 + cc];
    *(float4*)&TB[rr][cc] = *(const float4*)&N[(r0 + rr) * 256 + b0 + cc];
    __syncthreads();
#pragma unroll 8
    for (int r = 0; r < 32; r++) {
      const float av = TA[r][ar];
      const float4 bv = *(const float4*)&TB[r][c4];
      s0 += av * bv.x; s1 += av * bv.y; s2 += av * bv.z; s3 += av * bv.w;
    }
    __syncthreads();
  }
  float4 o; o.x = s0; o.y = s1; o.z = s2; o.w = s3;
  *(float4*)&M0[(a0 + ar) * 256 + b0 + c4] = o;
  if (ab == bb) {
    const int d = ar - c4;
    if (d >= 0 && d < 4) dbuf[ar] = (d == 0) ? s0 : (d == 1) ? s1 : (d == 2) ? s2 : s3;
    __syncthreads();
    if (t == 0) { float s = 0.f; for (int i = 0; i < 32; i++) s += dbuf[i]; part[ab] = s; }
  }
}

// Y = (X/c)^2 where c = sum(pIn[0..7]);  pOut gets trace partials of Y.
__global__ void k_sq(const float* __restrict__ X, float* __restrict__ Y,
                     const float* __restrict__ pIn, float* __restrict__ pOut) {
  __shared__ float TA[32][36], TB[32][36], dbuf[32];
  float c = 0.f;
#pragma unroll
  for (int i = 0; i < 8; i++) c += pIn[i];
  const float ic2 = 1.0f / (c * c);
  const int t  = threadIdx.x;
  const int ab = blockIdx.x >> 3, bb = blockIdx.x & 7;
  const int a0 = ab * 32, b0 = bb * 32;
  const int ar = t >> 3, c4 = (t & 7) << 2;
  float s0 = 0.f, s1 = 0.f, s2 = 0.f, s3 = 0.f;
  for (int m0 = 0; m0 < 256; m0 += 32) {
    const int rr = t >> 3, cc = (t & 7) << 2;
    *(float4*)&TA[rr][cc] = *(const float4*)&X[(a0 + rr) * 256 + m0 + cc];
    *(float4*)&TB[rr][cc] = *(const float4*)&X[(m0 + rr) * 256 + b0 + cc];
    __syncthreads();
#pragma unroll 8
    for (int m = 0; m < 32; m++) {
      const float av = TA[ar][m];
      const float4 bv = *(const float4*)&TB[m][c4];
      s0 += av * bv.x; s1 += av * bv.y; s2 += av * bv.z; s3 += av * bv.w;
    }
    __syncthreads();
  }
  s0 *= ic2; s1 *= ic2; s2 *= ic2; s3 *= ic2;
  float4 o; o.x = s0; o.y = s1; o.z = s2; o.w = s3;
  *(float4*)&Y[(a0 + ar) * 256 + b0 + c4] = o;
  if (ab == bb) {
    const int d = ar - c4;
    if (d >= 0 && d < 4) dbuf[ar] = (d == 0) ? s0 : (d == 1) ? s1 : (d == 2) ? s2 : s3;
    __syncthreads();
    if (t == 0) { float s = 0.f; for (int i = 0; i < 32; i++) s += dbuf[i]; pOut[ab] = s; }
  }
}

// ================= Sinv: register GJ (unpivoted) =================
// __launch_bounds__(256,1): single resident block -> up to ~512 VGPR/thread,
// keeps the 32x float4 working set in registers (was spilling to scratch at 64 VGPR,
// costing 2ms of the 3.4ms round-1 runtime).
__global__ __launch_bounds__(256, 1) void k_gj(const float* __restrict__ S, float* __restrict__ Z) {
  __shared__ float LCol[128];
  const int c = threadIdx.x;
  float4 a4[32];
  if (c < 128) {
#pragma unroll
    for (int q = 0; q < 32; q++) {
      a4[q].x = S[(4 * q + 0) * 128 + c]; a4[q].y = S[(4 * q + 1) * 128 + c];
      a4[q].z = S[(4 * q + 2) * 128 + c]; a4[q].w = S[(4 * q + 3) * 128 + c];
    }
  } else {
    const int d = c - 128;
#pragma unroll
    for (int q = 0; q < 32; q++) {
      a4[q].x = (d == 4 * q + 0) ? 1.f : 0.f; a4[q].y = (d == 4 * q + 1) ? 1.f : 0.f;
      a4[q].z = (d == 4 * q + 2) ? 1.f : 0.f; a4[q].w = (d == 4 * q + 3) ? 1.f : 0.f;
    }
  }
  for (int p = 0; p < 128; p++) {
    if (c == p) {
#pragma unroll
      for (int q = 0; q < 32; q++) *(float4*)&LCol[4 * q] = a4[q];
    }
    __syncthreads();
    float4 sq = a4[0];
#pragma unroll
    for (int q = 1; q < 32; q++) if ((p >> 2) == q) sq = a4[q];
    const int pm = p & 3;
    const float ap = pm == 0 ? sq.x : pm == 1 ? sq.y : pm == 2 ? sq.z : sq.w;
    const float aps = ap / LCol[p];
#pragma unroll
    for (int q = 0; q < 32; q++) {
      const float4 L = *(const float4*)&LCol[4 * q];
      float4 v = a4[q];
      v.x = (4 * q + 0 == p) ? aps : v.x - L.x * aps;
      v.y = (4 * q + 1 == p) ? aps : v.y - L.y * aps;
      v.z = (4 * q + 2 == p) ? aps : v.z - L.z * aps;
      v.w = (4 * q + 3 == p) ? aps : v.w - L.w * aps;
      a4[q] = v;
    }
    __syncthreads();
  }
  if (c >= 128) {
    const int cc = c - 128;
#pragma unroll
    for (int q = 0; q < 32; q++) {
      Z[(4 * q + 0) * 128 + cc] = a4[q].x; Z[(4 * q + 1) * 128 + cc] = a4[q].y;
      Z[(4 * q + 2) * 128 + cc] = a4[q].z; Z[(4 * q + 3) * 128 + cc] = a4[q].w;
    }
  }
}

// ================= generic 128x128 GEMM: Dst = A@B  (mode1: Dst = 2C - A@B) =================
__global__ void k_mm(const float* __restrict__ A, const float* __restrict__ Bm,
                     float* __restrict__ Dst, const float* __restrict__ C, int mode) {
  __shared__ float TA[32][36], TB[32][36];
  const int t  = threadIdx.x;
  const int ab = blockIdx.x >> 2, bb = blockIdx.x & 3;
  const int a0 = ab * 32, b0 = bb * 32;
  const int ar = t >> 3, c4 = (t & 7) << 2;
  float s0 = 0.f, s1 = 0.f, s2 = 0.f, s3 = 0.f;
  for (int m0 = 0; m0 < 128; m0 += 32) {
    const int rr = t >> 3, cc = (t & 7) << 2;
    *(float4*)&TA[rr][cc] = *(const float4*)&A[(a0 + rr) * 128 + m0 + cc];
    *(float4*)&TB[rr][cc] = *(const float4*)&Bm[(m0 + rr) * 128 + b0 + cc];
    __syncthreads();
#pragma unroll 8
    for (int m = 0; m < 32; m++) {
      const float av = TA[ar][m];
      const float4 bv = *(const float4*)&TB[m][c4];
      s0 += av * bv.x; s1 += av * bv.y; s2 += av * bv.z; s3 += av * bv.w;
    }
    __syncthreads();
  }
  const int oi = (a0 + ar) * 128 + b0 + c4;
  if (mode == 1) {
    s0 = 2.f * C[oi + 0] - s0; s1 = 2.f * C[oi + 1] - s1;
    s2 = 2.f * C[oi + 2] - s2; s3 = 2.f * C[oi + 3] - s3;
  }
  float4 o; o.x = s0; o.y = s1; o.z = s2; o.w = s3;
  *(float4*)&Dst[oi] = o;
}

// ================= build operators =================
__global__ void k_ops(const float* __restrict__ Kraw, const float* __restrict__ S,
                      const float* __restrict__ x0, const float* __restrict__ part,
                      const float* __restrict__ Z, float* __restrict__ WA, float* __restrict__ WB,
                      float* __restrict__ WC, float* __restrict__ WD,
                      float* __restrict__ SinvT, float* __restrict__ v0) {
  // sigma from trace chain: log2 l1 = sum_j 2^-j log2 c_j
  double logl = 0.0, w = 1.0;
  for (int k = 0; k <= 10; k++) {
    double c = 0.0;
    for (int i = 0; i < 8; i++) c += (double)part[k * 8 + i];
    logl += w * log2(c); w *= 0.5;
  }
  double sigma = exp2(0.5 * logl);
  if (sigma < 1e-5) sigma = 1e-5;
  const float invs = (float)(1.0 / (sigma + 0.002));
  const int wg = blockIdx.x, t = threadIdx.x;
  if (wg < 4) {
    float* dst = wg == 0 ? WA : wg == 1 ? WB : wg == 2 ? WC : WD;
    const int ro = (wg >> 1) * 128, co = (wg & 1) * 128;
    for (int e = t; e < 16384; e += 256) {
      const int i = e >> 7, o = e & 127;
      dst[e] = Kraw[(ro + o) * 256 + co + i] * invs;   // dst[i][o] = Kblk[o][i]/s
    }
  } else if (wg == 4) {
    for (int e = t; e < 16384; e += 256) {
      const int i = e >> 7, o = e & 127;
      SinvT[e] = Z[o * 128 + i];
    }
  } else {
    for (int e = t; e < 4096; e += 256) {
      const int b = e >> 7, o = e & 127;
      float s = 0.f;
      for (int i = 0; i < 128; i++) s += x0[b * 128 + i] * S[o * 128 + i];
      v0[e] = s;   // v0 = x0 @ S^T
    }
  }
}

// ================= chunk scan (the big kernel) =================
// 512 threads/wg (2 waves/SIMD at 1 wg/CU) to hide ds_read latency.
// Each thread: 2 rows x 4 cols of the 32x128 per-step output.
// MODE 0: zero-init, write final state to contrib.  MODE 1: init from initp, store v_t to outv.
template <int MODE>
__global__ __launch_bounds__(512) void k_scan(const float* __restrict__ u,
                                              const float* __restrict__ WAg,
                                              const float* __restrict__ WBg,
                                              const float* __restrict__ initp,
                                              float* __restrict__ outv,
                                              float* __restrict__ contribp) {
  extern __shared__ float lds[];
  float* WAl  = lds;            // 128*128
  float* WBuf = lds + 16384;    // 64*128
  float* XU   = lds + 24576;    // 256*36  [i][r], r = row in wg (32)
  const int t   = threadIdx.x;
  const int w   = blockIdx.x;          // 0..255
  const int gr0 = w * 32;
  const int b   = gr0 >> 8;
  const int c0  = gr0 & 255;
  // load WA (persistent)
  for (int e = t * 4; e < 16384; e += 2048)
    *(float4*)&WAl[e] = *(const float4*)&WAg[e];
  // init v-half of XU
  for (int e = t * 4; e < 4096; e += 2048) {
    const int r = e >> 7, i = e & 127;
    if (MODE == 1) {
      const float4 a = *(const float4*)&initp[((gr0 + r) << 7) + i];
      XU[(i + 0) * 36 + r] = a.x; XU[(i + 1) * 36 + r] = a.y;
      XU[(i + 2) * 36 + r] = a.z; XU[(i + 3) * 36 + r] = a.w;
    } else {
      XU[(i + 0) * 36 + r] = 0.f; XU[(i + 1) * 36 + r] = 0.f;
      XU[(i + 2) * 36 + r] = 0.f; XU[(i + 3) * 36 + r] = 0.f;
    }
  }
  __syncthreads();
  const int rt = t >> 5, ot = t & 31;
  const int r0 = rt * 2, o0 = ot * 4;
  for (int j = 0; j < LCH; j++) {
    // store current v (pre-step state) and stage u_t
    for (int e = t * 4; e < 4096; e += 2048) {
      const int r = e >> 7, i = e & 127;
      const int gidx = (((b << 12) + (c0 + r) * LCH + j) << 7) + i;
      if (MODE == 1) {
        float4 a;
        a.x = XU[(i + 0) * 36 + r]; a.y = XU[(i + 1) * 36 + r];
        a.z = XU[(i + 2) * 36 + r]; a.w = XU[(i + 3) * 36 + r];
        *(float4*)&outv[gidx] = a;
      }
      const float4 uv = *(const float4*)&u[gidx];
      XU[(128 + i + 0) * 36 + r] = uv.x; XU[(128 + i + 1) * 36 + r] = uv.y;
      XU[(128 + i + 2) * 36 + r] = uv.z; XU[(128 + i + 3) * 36 + r] = uv.w;
    }
    __syncthreads();   // A
    float4 acc0, acc1;
    acc0.x = acc0.y = acc0.z = acc0.w = 0.f;
    acc1.x = acc1.y = acc1.z = acc1.w = 0.f;
#pragma unroll 4
    for (int i = 0; i < 128; i++) {
      const float2 xv = *(const float2*)&XU[i * 36 + r0];
      const float4 wv = *(const float4*)&WAl[(i << 7) + o0];
      acc0.x += xv.x * wv.x; acc0.y += xv.x * wv.y; acc0.z += xv.x * wv.z; acc0.w += xv.x * wv.w;
      acc1.x += xv.y * wv.x; acc1.y += xv.y * wv.y; acc1.z += xv.y * wv.z; acc1.w += xv.y * wv.w;
    }
    // u-half in two WB chunks
    for (int half = 0; half < 2; half++) {
      for (int e = t * 4; e < 8192; e += 2048)
        *(float4*)&WBuf[e] = *(const float4*)&WBg[half * 8192 + e];
      __syncthreads();  // C / E
      const int ibase = 128 + half * 64;
#pragma unroll 4
      for (int i = 0; i < 64; i++) {
        const float2 xv = *(const float2*)&XU[(ibase + i) * 36 + r0];
        const float4 wv = *(const float4*)&WBuf[(i << 7) + o0];
        acc0.x += xv.x * wv.x; acc0.y += xv.x * wv.y; acc0.z += xv.x * wv.z; acc0.w += xv.x * wv.w;
        acc1.x += xv.y * wv.x; acc1.y += xv.y * wv.y; acc1.z += xv.y * wv.z; acc1.w += xv.y * wv.w;
      }
      if (half == 0) __syncthreads();  // D (before restage)
    }
    // writeback new v into XU v-half (all threads past C => v-reads done)
    XU[(o0 + 0) * 36 + r0 + 0] = acc0.x; XU[(o0 + 1) * 36 + r0 + 0] = acc0.y;
    XU[(o0 + 2) * 36 + r0 + 0] = acc0.z; XU[(o0 + 3) * 36 + r0 + 0] = acc0.w;
    XU[(o0 + 0) * 36 + r0 + 1] = acc1.x; XU[(o0 + 1) * 36 + r0 + 1] = acc1.y;
    XU[(o0 + 2) * 36 + r0 + 1] = acc1.z; XU[(o0 + 3) * 36 + r0 + 1] = acc1.w;
    __syncthreads();  // F
  }
  if (MODE == 0) {
    for (int e = t * 4; e < 4096; e += 2048) {
      const int r = e >> 7, i = e & 127;
      float4 a;
      a.x = XU[(i + 0) * 36 + r]; a.y = XU[(i + 1) * 36 + r];
      a.z = XU[(i + 2) * 36 + r]; a.w = XU[(i + 3) * 36 + r];
      *(float4*)&contribp[((gr0 + r) << 7) + i] = a;
    }
  }
}

// ================= phase-2 combine (matvec scans over chunks) =================
// mode0: sc[b][g]   = scan16(0, contrib, P16)
// mode1: Ssup[b][g] = states of super-scan(v0, sc, P256), stored pre-update
// mode2: schunk     = states of scan16(Ssup[b][g], contrib, P16), stored pre-update
__global__ void k_comb(const float* __restrict__ P, const float* __restrict__ initv,
                       const float* __restrict__ add, float* __restrict__ st,
                       float* __restrict__ fin, int mode) {
  extern __shared__ float lds[];
  float* Pl = lds;            // 128*132
  float* tc = lds + 16896;    // 128
  float* pb = lds + 17024;    // 256
  const int blk = blockIdx.x, t = threadIdx.x;
  const int o = t & 127, h = t >> 7;
  int addBase = 0, stBase = 0, iIdx = 0, fIdx = 0;
  if (mode == 0) { const int bb = blk >> 4, gg = blk & 15; addBase = bb * 256 + gg * 16; fIdx = bb * 16 + gg; }
  else if (mode == 1) { const int bb = blk; addBase = bb * 16; stBase = bb * 16; iIdx = bb; }
  else { const int bb = blk >> 4, gg = blk & 15; addBase = bb * 256 + gg * 16; stBase = addBase; iIdx = bb * 16 + gg; }
  for (int e = t * 4; e < 16384; e += 1024) {
    const int i = e >> 7, oo = e & 127;
    *(float4*)&Pl[i * 132 + oo] = *(const float4*)&P[e];
  }
  if (h == 0) tc[o] = (mode == 0) ? 0.f : initv[iIdx * 128 + o];
  __syncthreads();
  for (int k = 0; k < 16; k++) {
    float s = 0.f;
#pragma unroll 8
    for (int i = 0; i < 64; i++) {
      const int ii = h * 64 + i;
      s += tc[ii] * Pl[ii * 132 + o];
    }
    pb[h * 128 + o] = s;
    __syncthreads();
    if (h == 0) {
      if (mode != 0) st[(stBase + k) * 128 + o] = tc[o];
      tc[o] = pb[o] + pb[128 + o] + add[(addBase + k) * 128 + o];
    }
    __syncthreads();
  }
  if (mode == 0 && h == 0) fin[fIdx * 128 + o] = tc[o];
}

// ================= Y = V@WC + U@WD =================
// 512 threads/wg: each thread 2 rows x 8 cols of the 64x128 tile.
__global__ __launch_bounds__(512) void k_phy(const float* __restrict__ v, const float* __restrict__ u,
                                             const float* __restrict__ WCg, const float* __restrict__ WDg,
                                             float* __restrict__ y) {
  extern __shared__ float lds[];
  float* Wl = lds;            // 128*132
  float* VT = lds + 16896;    // 128*68
  const int t = threadIdx.x;
  const int m0 = blockIdx.x * 64;
  const int rt = t >> 4, ot = t & 15;
  const int r0 = rt * 2, o0 = ot * 8;
  float4 a0l, a0h, a1l, a1h;
  a0l.x = a0l.y = a0l.z = a0l.w = 0.f; a0h = a0l; a1l = a0l; a1h = a0l;
  for (int pass = 0; pass < 2; pass++) {
    const float* W = pass ? WDg : WCg;
    const float* A = pass ? u : v;
    for (int e = t * 4; e < 16384; e += 2048) {
      const int i = e >> 7, oo = e & 127;
      *(float4*)&Wl[i * 132 + oo] = *(const float4*)&W[e];
    }
    for (int e = t * 4; e < 8192; e += 2048) {
      const int r = e >> 7, i = e & 127;
      const float4 a = *(const float4*)&A[((m0 + r) << 7) + i];
      VT[(i + 0) * 68 + r] = a.x; VT[(i + 1) * 68 + r] = a.y;
      VT[(i + 2) * 68 + r] = a.z; VT[(i + 3) * 68 + r] = a.w;
    }
    __syncthreads();
#pragma unroll 2
    for (int i = 0; i < 128; i++) {
      const float2 xv = *(const float2*)&VT[i * 68 + r0];
      const float4 w0 = *(const float4*)&Wl[i * 132 + o0];
      const float4 w1 = *(const float4*)&Wl[i * 132 + o0 + 4];
      a0l.x += xv.x * w0.x; a0l.y += xv.x * w0.y; a0l.z += xv.x * w0.z; a0l.w += xv.x * w0.w;
      a0h.x += xv.x * w1.x; a0h.y += xv.x * w1.y; a0h.z += xv.x * w1.z; a0h.w += xv.x * w1.w;
      a1l.x += xv.y * w0.x; a1l.y += xv.y * w0.y; a1l.z += xv.y * w0.z; a1l.w += xv.y * w0.w;
      a1h.x += xv.y * w1.x; a1h.y += xv.y * w1.y; a1h.z += xv.y * w1.z; a1h.w += xv.y * w1.w;
    }
    __syncthreads();
  }
  *(float4*)&y[((m0 + r0 + 0) << 7) + o0] = a0l;
  *(float4*)&y[((m0 + r0 + 0) << 7) + o0 + 4] = a0h;
  *(float4*)&y[((m0 + r0 + 1) << 7) + o0] = a1l;
  *(float4*)&y[((m0 + r0 + 1) << 7) + o0 + 4] = a1h;
}

// ================= X = V @ SinvT  (in place on vx) =================
__global__ __launch_bounds__(512) void k_phx(float* __restrict__ vx, const float* __restrict__ Wg) {
  extern __shared__ float lds[];
  float* Wl = lds;
  float* VT = lds + 16896;
  const int t = threadIdx.x;
  const int m0 = blockIdx.x * 64;
  const int rt = t >> 4, ot = t & 15;
  const int r0 = rt * 2, o0 = ot * 8;
  float4 a0l, a0h, a1l, a1h;
  a0l.x = a0l.y = a0l.z = a0l.w = 0.f; a0h = a0l; a1l = a0l; a1h = a0l;
  for (int e = t * 4; e < 16384; e += 2048) {
    const int i = e >> 7, oo = e & 127;
    *(float4*)&Wl[i * 132 + oo] = *(const float4*)&Wg[e];
  }
  for (int e = t * 4; e < 8192; e += 2048) {
    const int r = e >> 7, i = e & 127;
    const float4 a = *(const float4*)&vx[((m0 + r) << 7) + i];
    VT[(i + 0) * 68 + r] = a.x; VT[(i + 1) * 68 + r] = a.y;
    VT[(i + 2) * 68 + r] = a.z; VT[(i + 3) * 68 + r] = a.w;
  }
  __syncthreads();
#pragma unroll 2
  for (int i = 0; i < 128; i++) {
    const float2 xv = *(const float2*)&VT[i * 68 + r0];
    const float4 w0 = *(const float4*)&Wl[i * 132 + o0];
    const float4 w1 = *(const float4*)&Wl[i * 132 + o0 + 4];
    a0l.x += xv.x * w0.x; a0l.y += xv.x * w0.y; a0l.z += xv.x * w0.z; a0l.w += xv.x * w0.w;
    a0h.x += xv.x * w1.x; a0h.y += xv.x * w1.y; a0h.z += xv.x * w1.z; a0h.w += xv.x * w1.w;
    a1l.x += xv.y * w0.x; a1l.y += xv.y * w0.y; a1l.z += xv.y * w0.z; a1l.w += xv.y * w0.w;
    a1h.x += xv.y * w1.x; a1h.y += xv.y * w1.y; a1h.z += xv.y * w1.z; a1h.w += xv.y * w1.w;
  }
  *(float4*)&vx[((m0 + r0 + 0) << 7) + o0] = a0l;
  *(float4*)&vx[((m0 + r0 + 0) << 7) + o0 + 4] = a0h;
  *(float4*)&vx[((m0 + r0 + 1) << 7) + o0] = a1l;
  *(float4*)&vx[((m0 + r0 + 1) << 7) + o0 + 4] = a1h;
}

// ================= host =================
extern "C" void kernel_launch(void* const* d_in, const int* in_sizes, int n_in,
                              void* d_out, int out_size, void* d_ws, size_t ws_size,
                              hipStream_t stream) {
  (void)in_sizes; (void)n_in; (void)out_size;
  const float* u    = (const float*)d_in[0];
  const float* x0   = (const float*)d_in[1];
  const float* S    = (const float*)d_in[2];
  const float* Kraw = (const float*)d_in[3];
  float* out = (float*)d_out;
  float* yout = out;                       // y_seq: 32*4096*128
  float* vx   = out + 16777216LL;          // x_seq region; holds v_seq until k_phx
  float* ws = (float*)d_ws;
  if (ws_size < (size_t)(WS_FLOATS * 4)) return;

  float* MSQ0 = ws + O_MSQ0;  float* MSQ1 = ws + O_MSQ1;  float* PART = ws + O_PART;
  float* Z0 = ws + O_Z0;      float* Z1 = ws + O_Z1;      float* TN = ws + O_TN;
  float* WA = ws + O_WA;      float* WB = ws + O_WB;      float* WC = ws + O_WC;
  float* WD = ws + O_WD;      float* SINVT = ws + O_SINVT; float* V0 = ws + O_V0;
  float* PW = ws + O_PW;
  float* CONTRIB = ws + O_CONTRIB;  float* SC = ws + O_SC;
  float* SSUP = ws + O_SSUP;        float* SCHUNK = ws + O_SCHUNK;

  // sigma trace chain
  k_m0<<<64, 256, 0, stream>>>(Kraw, MSQ0, PART);
  float* mb[2] = {MSQ0, MSQ1};
  for (int k = 1; k <= 10; k++)
    k_sq<<<64, 256, 0, stream>>>(mb[(k + 1) & 1], mb[k & 1], PART + (k - 1) * 8, PART + k * 8);

  // Sinv: GJ + 3x Newton-Schulz
  k_gj<<<1, 256, 0, stream>>>(S, Z0);
  k_mm<<<16, 256, 0, stream>>>(S, Z0, TN, nullptr, 0);
  k_mm<<<16, 256, 0, stream>>>(Z0, TN, Z1, Z0, 1);
  k_mm<<<16, 256, 0, stream>>>(S, Z1, TN, nullptr, 0);
  k_mm<<<16, 256, 0, stream>>>(Z1, TN, Z0, Z1, 1);
  k_mm<<<16, 256, 0, stream>>>(S, Z0, TN, nullptr, 0);
  k_mm<<<16, 256, 0, stream>>>(Z0, TN, Z1, Z0, 1);

  // operators (scaled transposed K blocks), SinvT, v0
  k_ops<<<6, 256, 0, stream>>>(Kraw, S, x0, PART, Z1, WA, WB, WC, WD, SINVT, V0);

  // powers of WA: P2..P256
  k_mm<<<16, 256, 0, stream>>>(WA, WA, PW + 0, nullptr, 0);
  k_mm<<<16, 256, 0, stream>>>(PW + 0, PW + 0, PW + 16384, nullptr, 0);
  k_mm<<<16, 256, 0, stream>>>(PW + 16384, PW + 16384, PW + 32768, nullptr, 0);
  k_mm<<<16, 256, 0, stream>>>(PW + 32768, PW + 32768, PW + 49152, nullptr, 0);   // P16
  k_mm<<<16, 256, 0, stream>>>(PW + 49152, PW + 49152, PW + 65536, nullptr, 0);
  k_mm<<<16, 256, 0, stream>>>(PW + 65536, PW + 65536, PW + 81920, nullptr, 0);
  k_mm<<<16, 256, 0, stream>>>(PW + 81920, PW + 81920, PW + 98304, nullptr, 0);
  k_mm<<<16, 256, 0, stream>>>(PW + 98304, PW + 98304, PW + 114688, nullptr, 0);  // P256
  float* P16 = PW + 49152;
  float* P256 = PW + 114688;

  const size_t scanLds = 135168;   // (16384 + 8192 + 256*36) * 4
  const size_t combLds = 69120;    // 17280 * 4
  const size_t gemmLds = 102400;   // (16896 + 8704) * 4

  // pass 1: chunk contributions
  k_scan<0><<<256, 512, scanLds, stream>>>(u, WA, WB, nullptr, nullptr, CONTRIB);
  // phase 2: hierarchical combine -> chunk-start states
  k_comb<<<512, 256, combLds, stream>>>(P16, nullptr, CONTRIB, nullptr, SC, 0);
  k_comb<<<32, 256, combLds, stream>>>(P256, V0, SC, SSUP, nullptr, 1);
  k_comb<<<512, 256, combLds, stream>>>(P16, SSUP, CONTRIB, SCHUNK, nullptr, 2);
  // pass 2: true states, stored to out (v-space)
  k_scan<1><<<256, 512, scanLds, stream>>>(u, WA, WB, SCHUNK, vx, nullptr);
  // outputs
  k_phy<<<2048, 512, gemmLds, stream>>>(vx, u, WC, WD, yout);
  k_phx<<<2048, 512, gemmLds, stream>>>(vx, SINVT);
}

// Round 4
// 1233.550 us; speedup vs baseline: 2.7951x; 1.1557x over previous
//
#include <hip/hip_runtime.h>

// L2BoundedLTICell: B=32, T=4096, d=128.
// v-space trick: v = x @ S^T  =>  v' = v K11^T + u K12^T ; y = v K21^T + u K22^T ; x = v Sinv^T.
// Chunked scan: L=16, 256 chunks/batch, 8192 rows.
// Round 3 resubmit (round-3 bench failed on GPU acquisition, no data): prep chain
// (27 tiny kernels, ~580us serialized) fused into 2 kernels with device-scope
// spin grid-barriers (grids <= 65 wgs, guaranteed co-resident).

#define B_   32
#define T_   4096
#define D_   128
#define LCH  16
#define NCH  256
#define NSIG 10

// ---- ws layout (floats) ----
#define O_MSQ0    0LL
#define O_MSQ1    65536LL
#define O_PART    131072LL          // 16*8 used (88); ints 96..127 = barrier counters
#define O_Z0      131200LL
#define O_Z1      147584LL
#define O_TN      163968LL
#define O_WA      180352LL
#define O_WB      196736LL
#define O_WC      213120LL
#define O_WD      229504LL
#define O_SINVT   245888LL
#define O_V0      262272LL
#define O_PW      266368LL          // 8 slots * 16384  (P2,P4,P8,P16,P32,P64,P128,P256)
#define O_CONTRIB 397440LL          // 8192*128
#define O_SC      1446016LL         // 32*16*128
#define O_SSUP    1511552LL
#define O_SCHUNK  1577088LL         // 8192*128
#define WS_FLOATS 2625664LL

// ================= device-scope grid barrier (all wgs co-resident) =================
// __threadfence() at agent scope emits the L2 writeback / L1+L2 invalidate needed
// for cross-XCD visibility on gfx950; atomicAdd on global is device-scope.
__device__ __forceinline__ void gbar(int* cnt, int n) {
  __syncthreads();                    // drains this wg's stores (vmcnt0 at barrier)
  if (threadIdx.x == 0) {
    __threadfence();                  // release: write back L2
    atomicAdd(cnt, 1);
    while (atomicAdd(cnt, 0) < n) { }
    __threadfence();                  // acquire: invalidate L1/L2 stale lines
  }
  __syncthreads();
  __threadfence();
}

// ================= 128x128 tile-mult helper: Dst = A@B (mode1: Dst = 2C - A@B) ====
// 16 local wgs, each 32x32 tile, 256 threads.
__device__ void mult32(const float* __restrict__ A, const float* __restrict__ Bm,
                       float* __restrict__ Dst, const float* __restrict__ C,
                       int mode, int wl) {
  __shared__ float MTA[32][36], MTB[32][36];
  const int t  = threadIdx.x;
  const int ab = wl >> 2, bb = wl & 3;
  const int a0 = ab * 32, b0 = bb * 32;
  const int ar = t >> 3, c4 = (t & 7) << 2;
  float s0 = 0.f, s1 = 0.f, s2 = 0.f, s3 = 0.f;
  for (int m0 = 0; m0 < 128; m0 += 32) {
    const int rr = t >> 3, cc = (t & 7) << 2;
    *(float4*)&MTA[rr][cc] = *(const float4*)&A[(a0 + rr) * 128 + m0 + cc];
    *(float4*)&MTB[rr][cc] = *(const float4*)&Bm[(m0 + rr) * 128 + b0 + cc];
    __syncthreads();
#pragma unroll 8
    for (int m = 0; m < 32; m++) {
      const float av = MTA[ar][m];
      const float4 bv = *(const float4*)&MTB[m][c4];
      s0 += av * bv.x; s1 += av * bv.y; s2 += av * bv.z; s3 += av * bv.w;
    }
    __syncthreads();
  }
  const int oi = (a0 + ar) * 128 + b0 + c4;
  if (mode == 1) {
    s0 = 2.f * C[oi + 0] - s0; s1 = 2.f * C[oi + 1] - s1;
    s2 = 2.f * C[oi + 2] - s2; s3 = 2.f * C[oi + 3] - s3;
  }
  float4 o; o.x = s0; o.y = s1; o.z = s2; o.w = s3;
  *(float4*)&Dst[oi] = o;
}

// ================= prep kernel 1 =================
// wgs 0..63: sigma trace-squaring chain (11 grid barriers) then build WA..WD, v0.
// wg 64: register Gauss-Jordan inverse S -> Z0 (runs concurrently, no barriers).
__global__ __launch_bounds__(256, 1) void k_prep1(
    const float* __restrict__ Kraw, const float* __restrict__ S,
    const float* __restrict__ x0,
    float* __restrict__ MSQ0, float* __restrict__ MSQ1, float* __restrict__ PART,
    float* __restrict__ Z0, float* __restrict__ WA, float* __restrict__ WB,
    float* __restrict__ WC, float* __restrict__ WD, float* __restrict__ V0,
    int* __restrict__ BAR) {
  const int wg = blockIdx.x, t = threadIdx.x;

  if (wg == 64) {
    // ---- Gauss-Jordan, register-resident (needs only S) ----
    __shared__ float LCol[128];
    const int c = t;
    float4 a4[32];
    if (c < 128) {
#pragma unroll
      for (int q = 0; q < 32; q++) {
        a4[q].x = S[(4 * q + 0) * 128 + c]; a4[q].y = S[(4 * q + 1) * 128 + c];
        a4[q].z = S[(4 * q + 2) * 128 + c]; a4[q].w = S[(4 * q + 3) * 128 + c];
      }
    } else {
      const int d = c - 128;
#pragma unroll
      for (int q = 0; q < 32; q++) {
        a4[q].x = (d == 4 * q + 0) ? 1.f : 0.f; a4[q].y = (d == 4 * q + 1) ? 1.f : 0.f;
        a4[q].z = (d == 4 * q + 2) ? 1.f : 0.f; a4[q].w = (d == 4 * q + 3) ? 1.f : 0.f;
      }
    }
    for (int p = 0; p < 128; p++) {
      if (c == p) {
#pragma unroll
        for (int q = 0; q < 32; q++) *(float4*)&LCol[4 * q] = a4[q];
      }
      __syncthreads();
      float4 sq = a4[0];
#pragma unroll
      for (int q = 1; q < 32; q++) if ((p >> 2) == q) sq = a4[q];
      const int pm = p & 3;
      const float ap = pm == 0 ? sq.x : pm == 1 ? sq.y : pm == 2 ? sq.z : sq.w;
      const float aps = ap / LCol[p];
#pragma unroll
      for (int q = 0; q < 32; q++) {
        const float4 L = *(const float4*)&LCol[4 * q];
        float4 v = a4[q];
        v.x = (4 * q + 0 == p) ? aps : v.x - L.x * aps;
        v.y = (4 * q + 1 == p) ? aps : v.y - L.y * aps;
        v.z = (4 * q + 2 == p) ? aps : v.z - L.z * aps;
        v.w = (4 * q + 3 == p) ? aps : v.w - L.w * aps;
        a4[q] = v;
      }
      __syncthreads();
    }
    if (c >= 128) {
      const int cc = c - 128;
#pragma unroll
      for (int q = 0; q < 32; q++) {
        Z0[(4 * q + 0) * 128 + cc] = a4[q].x; Z0[(4 * q + 1) * 128 + cc] = a4[q].y;
        Z0[(4 * q + 2) * 128 + cc] = a4[q].z; Z0[(4 * q + 3) * 128 + cc] = a4[q].w;
      }
    }
    return;
  }

  // ---- sigma wgs (0..63): 8x8 tiling of 256x256 ----
  __shared__ float TA[32][36], TB[32][36], dbuf[32];
  const int ab = wg >> 3, bb = wg & 7;
  const int a0 = ab * 32, b0 = bb * 32;
  const int ar = t >> 3, c4 = (t & 7) << 2;

  // round 0: M0 = Kraw^T Kraw, trace partials -> PART[0..7]
  {
    float s0 = 0.f, s1 = 0.f, s2 = 0.f, s3 = 0.f;
    for (int r0 = 0; r0 < 256; r0 += 32) {
      const int rr = t >> 3, cc = (t & 7) << 2;
      *(float4*)&TA[rr][cc] = *(const float4*)&Kraw[(r0 + rr) * 256 + a0 + cc];
      *(float4*)&TB[rr][cc] = *(const float4*)&Kraw[(r0 + rr) * 256 + b0 + cc];
      __syncthreads();
#pragma unroll 8
      for (int r = 0; r < 32; r++) {
        const float av = TA[r][ar];
        const float4 bv = *(const float4*)&TB[r][c4];
        s0 += av * bv.x; s1 += av * bv.y; s2 += av * bv.z; s3 += av * bv.w;
      }
      __syncthreads();
    }
    float4 o; o.x = s0; o.y = s1; o.z = s2; o.w = s3;
    *(float4*)&MSQ0[(a0 + ar) * 256 + b0 + c4] = o;
    if (ab == bb) {
      const int d = ar - c4;
      if (d >= 0 && d < 4) dbuf[ar] = (d == 0) ? s0 : (d == 1) ? s1 : (d == 2) ? s2 : s3;
      __syncthreads();
      if (t == 0) { float s = 0.f; for (int i = 0; i < 32; i++) s += dbuf[i]; PART[ab] = s; }
    }
  }
  gbar(BAR + 0, 64);

  // rounds 1..NSIG: Y = (X/c)^2
  float* bufs[2] = {MSQ0, MSQ1};
  for (int k = 1; k <= NSIG; k++) {
    const float* X = bufs[(k + 1) & 1];
    float* Y = bufs[k & 1];
    float c = 0.f;
#pragma unroll
    for (int i = 0; i < 8; i++) c += PART[(k - 1) * 8 + i];
    const float ic2 = 1.0f / (c * c);
    float s0 = 0.f, s1 = 0.f, s2 = 0.f, s3 = 0.f;
    for (int m0 = 0; m0 < 256; m0 += 32) {
      const int rr = t >> 3, cc = (t & 7) << 2;
      *(float4*)&TA[rr][cc] = *(const float4*)&X[(a0 + rr) * 256 + m0 + cc];
      *(float4*)&TB[rr][cc] = *(const float4*)&X[(m0 + rr) * 256 + b0 + cc];
      __syncthreads();
#pragma unroll 8
      for (int m = 0; m < 32; m++) {
        const float av = TA[ar][m];
        const float4 bv = *(const float4*)&TB[m][c4];
        s0 += av * bv.x; s1 += av * bv.y; s2 += av * bv.z; s3 += av * bv.w;
      }
      __syncthreads();
    }
    s0 *= ic2; s1 *= ic2; s2 *= ic2; s3 *= ic2;
    float4 o; o.x = s0; o.y = s1; o.z = s2; o.w = s3;
    *(float4*)&Y[(a0 + ar) * 256 + b0 + c4] = o;
    if (ab == bb) {
      const int d = ar - c4;
      if (d >= 0 && d < 4) dbuf[ar] = (d == 0) ? s0 : (d == 1) ? s1 : (d == 2) ? s2 : s3;
      __syncthreads();
      if (t == 0) { float s = 0.f; for (int i = 0; i < 32; i++) s += dbuf[i]; PART[k * 8 + ab] = s; }
    }
    gbar(BAR + k, 64);
  }

  // ---- ops: sigma from trace chain, build scaled transposed K blocks + v0 ----
  if (wg < 5) {
    double logl = 0.0, w = 1.0;
    for (int k = 0; k <= NSIG; k++) {
      double c = 0.0;
      for (int i = 0; i < 8; i++) c += (double)PART[k * 8 + i];
      logl += w * log2(c); w *= 0.5;
    }
    double sigma = exp2(0.5 * logl);
    if (sigma < 1e-5) sigma = 1e-5;
    const float invs = (float)(1.0 / (sigma + 0.002));
    if (wg < 4) {
      float* dst = wg == 0 ? WA : wg == 1 ? WB : wg == 2 ? WC : WD;
      const int ro = (wg >> 1) * 128, co = (wg & 1) * 128;
      for (int e = t; e < 16384; e += 256) {
        const int i = e >> 7, o = e & 127;
        dst[e] = Kraw[(ro + o) * 256 + co + i] * invs;   // dst[i][o] = Kblk[o][i]/s
      }
    } else {
      for (int e = t; e < 4096; e += 256) {
        const int b = e >> 7, o = e & 127;
        float s = 0.f;
        for (int i = 0; i < 128; i++) s += x0[b * 128 + i] * S[o * 128 + i];
        V0[e] = s;   // v0 = x0 @ S^T
      }
    }
  }
}

// ================= prep kernel 2 =================
// wgs 0..15 (group A): Newton-Schulz x3 on Z0 -> Z1, then SINVT = Z1^T.
// wgs 16..31 (group B): WA power chain P2..P256 (concurrent, own barriers).
__global__ __launch_bounds__(256, 1) void k_prep2(
    const float* __restrict__ S, float* __restrict__ Z0, float* __restrict__ Z1,
    float* __restrict__ TN, const float* __restrict__ WA, float* __restrict__ PW,
    float* __restrict__ SINVT, int* __restrict__ BARA, int* __restrict__ BARB) {
  const int wg = blockIdx.x, t = threadIdx.x;
  if (wg < 16) {
    mult32(S, Z0, TN, nullptr, 0, wg);  gbar(BARA + 0, 16);
    mult32(Z0, TN, Z1, Z0, 1, wg);      gbar(BARA + 1, 16);
    mult32(S, Z1, TN, nullptr, 0, wg);  gbar(BARA + 2, 16);
    mult32(Z1, TN, Z0, Z1, 1, wg);      gbar(BARA + 3, 16);
    mult32(S, Z0, TN, nullptr, 0, wg);  gbar(BARA + 4, 16);
    mult32(Z0, TN, Z1, Z0, 1, wg);      gbar(BARA + 5, 16);
    for (int e = wg * 256 + t; e < 16384; e += 4096)
      SINVT[e] = Z1[(e & 127) * 128 + (e >> 7)];
  } else {
    const int wl = wg - 16;
    mult32(WA, WA, PW, nullptr, 0, wl);                          gbar(BARB + 0, 16);
#pragma unroll 1
    for (int q = 1; q < 8; q++) {
      mult32(PW + (q - 1) * 16384, PW + (q - 1) * 16384, PW + q * 16384, nullptr, 0, wl);
      if (q < 7) gbar(BARB + q, 16);
    }
  }
}

// ================= chunk scan (the big kernel) =================
// 512 threads/wg (2 waves/SIMD at 1 wg/CU). Each thread: 2 rows x 4 cols.
// MODE 0: zero-init, write final state to contrib.  MODE 1: init from initp, store v_t to outv.
template <int MODE>
__global__ __launch_bounds__(512) void k_scan(const float* __restrict__ u,
                                              const float* __restrict__ WAg,
                                              const float* __restrict__ WBg,
                                              const float* __restrict__ initp,
                                              float* __restrict__ outv,
                                              float* __restrict__ contribp) {
  extern __shared__ float lds[];
  float* WAl  = lds;            // 128*128
  float* WBuf = lds + 16384;    // 64*128
  float* XU   = lds + 24576;    // 256*36  [i][r], r = row in wg (32)
  const int t   = threadIdx.x;
  const int w   = blockIdx.x;          // 0..255
  const int gr0 = w * 32;
  const int b   = gr0 >> 8;
  const int c0  = gr0 & 255;
  for (int e = t * 4; e < 16384; e += 2048)
    *(float4*)&WAl[e] = *(const float4*)&WAg[e];
  for (int e = t * 4; e < 4096; e += 2048) {
    const int r = e >> 7, i = e & 127;
    if (MODE == 1) {
      const float4 a = *(const float4*)&initp[((gr0 + r) << 7) + i];
      XU[(i + 0) * 36 + r] = a.x; XU[(i + 1) * 36 + r] = a.y;
      XU[(i + 2) * 36 + r] = a.z; XU[(i + 3) * 36 + r] = a.w;
    } else {
      XU[(i + 0) * 36 + r] = 0.f; XU[(i + 1) * 36 + r] = 0.f;
      XU[(i + 2) * 36 + r] = 0.f; XU[(i + 3) * 36 + r] = 0.f;
    }
  }
  __syncthreads();
  const int rt = t >> 5, ot = t & 31;
  const int r0 = rt * 2, o0 = ot * 4;
  for (int j = 0; j < LCH; j++) {
    for (int e = t * 4; e < 4096; e += 2048) {
      const int r = e >> 7, i = e & 127;
      const int gidx = (((b << 12) + (c0 + r) * LCH + j) << 7) + i;
      if (MODE == 1) {
        float4 a;
        a.x = XU[(i + 0) * 36 + r]; a.y = XU[(i + 1) * 36 + r];
        a.z = XU[(i + 2) * 36 + r]; a.w = XU[(i + 3) * 36 + r];
        *(float4*)&outv[gidx] = a;
      }
      const float4 uv = *(const float4*)&u[gidx];
      XU[(128 + i + 0) * 36 + r] = uv.x; XU[(128 + i + 1) * 36 + r] = uv.y;
      XU[(128 + i + 2) * 36 + r] = uv.z; XU[(128 + i + 3) * 36 + r] = uv.w;
    }
    __syncthreads();   // A
    float4 acc0, acc1;
    acc0.x = acc0.y = acc0.z = acc0.w = 0.f;
    acc1.x = acc1.y = acc1.z = acc1.w = 0.f;
#pragma unroll 4
    for (int i = 0; i < 128; i++) {
      const float2 xv = *(const float2*)&XU[i * 36 + r0];
      const float4 wv = *(const float4*)&WAl[(i << 7) + o0];
      acc0.x += xv.x * wv.x; acc0.y += xv.x * wv.y; acc0.z += xv.x * wv.z; acc0.w += xv.x * wv.w;
      acc1.x += xv.y * wv.x; acc1.y += xv.y * wv.y; acc1.z += xv.y * wv.z; acc1.w += xv.y * wv.w;
    }
    for (int half = 0; half < 2; half++) {
      for (int e = t * 4; e < 8192; e += 2048)
        *(float4*)&WBuf[e] = *(const float4*)&WBg[half * 8192 + e];
      __syncthreads();  // C / E
      const int ibase = 128 + half * 64;
#pragma unroll 4
      for (int i = 0; i < 64; i++) {
        const float2 xv = *(const float2*)&XU[(ibase + i) * 36 + r0];
        const float4 wv = *(const float4*)&WBuf[(i << 7) + o0];
        acc0.x += xv.x * wv.x; acc0.y += xv.x * wv.y; acc0.z += xv.x * wv.z; acc0.w += xv.x * wv.w;
        acc1.x += xv.y * wv.x; acc1.y += xv.y * wv.y; acc1.z += xv.y * wv.z; acc1.w += xv.y * wv.w;
      }
      if (half == 0) __syncthreads();  // D (before restage)
    }
    XU[(o0 + 0) * 36 + r0 + 0] = acc0.x; XU[(o0 + 1) * 36 + r0 + 0] = acc0.y;
    XU[(o0 + 2) * 36 + r0 + 0] = acc0.z; XU[(o0 + 3) * 36 + r0 + 0] = acc0.w;
    XU[(o0 + 0) * 36 + r0 + 1] = acc1.x; XU[(o0 + 1) * 36 + r0 + 1] = acc1.y;
    XU[(o0 + 2) * 36 + r0 + 1] = acc1.z; XU[(o0 + 3) * 36 + r0 + 1] = acc1.w;
    __syncthreads();  // F
  }
  if (MODE == 0) {
    for (int e = t * 4; e < 4096; e += 2048) {
      const int r = e >> 7, i = e & 127;
      float4 a;
      a.x = XU[(i + 0) * 36 + r]; a.y = XU[(i + 1) * 36 + r];
      a.z = XU[(i + 2) * 36 + r]; a.w = XU[(i + 3) * 36 + r];
      *(float4*)&contribp[((gr0 + r) << 7) + i] = a;
    }
  }
}

// ================= phase-2 combine (matvec scans over chunks) =================
__global__ void k_comb(const float* __restrict__ P, const float* __restrict__ initv,
                       const float* __restrict__ add, float* __restrict__ st,
                       float* __restrict__ fin, int mode) {
  extern __shared__ float lds[];
  float* Pl = lds;            // 128*132
  float* tc = lds + 16896;    // 128
  float* pb = lds + 17024;    // 256
  const int blk = blockIdx.x, t = threadIdx.x;
  const int o = t & 127, h = t >> 7;
  int addBase = 0, stBase = 0, iIdx = 0, fIdx = 0;
  if (mode == 0) { const int bb = blk >> 4, gg = blk & 15; addBase = bb * 256 + gg * 16; fIdx = bb * 16 + gg; }
  else if (mode == 1) { const int bb = blk; addBase = bb * 16; stBase = bb * 16; iIdx = bb; }
  else { const int bb = blk >> 4, gg = blk & 15; addBase = bb * 256 + gg * 16; stBase = addBase; iIdx = bb * 16 + gg; }
  for (int e = t * 4; e < 16384; e += 1024) {
    const int i = e >> 7, oo = e & 127;
    *(float4*)&Pl[i * 132 + oo] = *(const float4*)&P[e];
  }
  if (h == 0) tc[o] = (mode == 0) ? 0.f : initv[iIdx * 128 + o];
  __syncthreads();
  for (int k = 0; k < 16; k++) {
    float s = 0.f;
#pragma unroll 8
    for (int i = 0; i < 64; i++) {
      const int ii = h * 64 + i;
      s += tc[ii] * Pl[ii * 132 + o];
    }
    pb[h * 128 + o] = s;
    __syncthreads();
    if (h == 0) {
      if (mode != 0) st[(stBase + k) * 128 + o] = tc[o];
      tc[o] = pb[o] + pb[128 + o] + add[(addBase + k) * 128 + o];
    }
    __syncthreads();
  }
  if (mode == 0 && h == 0) fin[fIdx * 128 + o] = tc[o];
}

// ================= Y = V@WC + U@WD =================
__global__ __launch_bounds__(512) void k_phy(const float* __restrict__ v, const float* __restrict__ u,
                                             const float* __restrict__ WCg, const float* __restrict__ WDg,
                                             float* __restrict__ y) {
  extern __shared__ float lds[];
  float* Wl = lds;            // 128*132
  float* VT = lds + 16896;    // 128*68
  const int t = threadIdx.x;
  const int m0 = blockIdx.x * 64;
  const int rt = t >> 4, ot = t & 15;
  const int r0 = rt * 2, o0 = ot * 8;
  float4 a0l, a0h, a1l, a1h;
  a0l.x = a0l.y = a0l.z = a0l.w = 0.f; a0h = a0l; a1l = a0l; a1h = a0l;
  for (int pass = 0; pass < 2; pass++) {
    const float* W = pass ? WDg : WCg;
    const float* A = pass ? u : v;
    for (int e = t * 4; e < 16384; e += 2048) {
      const int i = e >> 7, oo = e & 127;
      *(float4*)&Wl[i * 132 + oo] = *(const float4*)&W[e];
    }
    for (int e = t * 4; e < 8192; e += 2048) {
      const int r = e >> 7, i = e & 127;
      const float4 a = *(const float4*)&A[((m0 + r) << 7) + i];
      VT[(i + 0) * 68 + r] = a.x; VT[(i + 1) * 68 + r] = a.y;
      VT[(i + 2) * 68 + r] = a.z; VT[(i + 3) * 68 + r] = a.w;
    }
    __syncthreads();
#pragma unroll 2
    for (int i = 0; i < 128; i++) {
      const float2 xv = *(const float2*)&VT[i * 68 + r0];
      const float4 w0 = *(const float4*)&Wl[i * 132 + o0];
      const float4 w1 = *(const float4*)&Wl[i * 132 + o0 + 4];
      a0l.x += xv.x * w0.x; a0l.y += xv.x * w0.y; a0l.z += xv.x * w0.z; a0l.w += xv.x * w0.w;
      a0h.x += xv.x * w1.x; a0h.y += xv.x * w1.y; a0h.z += xv.x * w1.z; a0h.w += xv.x * w1.w;
      a1l.x += xv.y * w0.x; a1l.y += xv.y * w0.y; a1l.z += xv.y * w0.z; a1l.w += xv.y * w0.w;
      a1h.x += xv.y * w1.x; a1h.y += xv.y * w1.y; a1h.z += xv.y * w1.z; a1h.w += xv.y * w1.w;
    }
    __syncthreads();
  }
  *(float4*)&y[((m0 + r0 + 0) << 7) + o0] = a0l;
  *(float4*)&y[((m0 + r0 + 0) << 7) + o0 + 4] = a0h;
  *(float4*)&y[((m0 + r0 + 1) << 7) + o0] = a1l;
  *(float4*)&y[((m0 + r0 + 1) << 7) + o0 + 4] = a1h;
}

// ================= X = V @ SinvT  (in place on vx) =================
__global__ __launch_bounds__(512) void k_phx(float* __restrict__ vx, const float* __restrict__ Wg) {
  extern __shared__ float lds[];
  float* Wl = lds;
  float* VT = lds + 16896;
  const int t = threadIdx.x;
  const int m0 = blockIdx.x * 64;
  const int rt = t >> 4, ot = t & 15;
  const int r0 = rt * 2, o0 = ot * 8;
  float4 a0l, a0h, a1l, a1h;
  a0l.x = a0l.y = a0l.z = a0l.w = 0.f; a0h = a0l; a1l = a0l; a1h = a0l;
  for (int e = t * 4; e < 16384; e += 2048) {
    const int i = e >> 7, oo = e & 127;
    *(float4*)&Wl[i * 132 + oo] = *(const float4*)&Wg[e];
  }
  for (int e = t * 4; e < 8192; e += 2048) {
    const int r = e >> 7, i = e & 127;
    const float4 a = *(const float4*)&vx[((m0 + r) << 7) + i];
    VT[(i + 0) * 68 + r] = a.x; VT[(i + 1) * 68 + r] = a.y;
    VT[(i + 2) * 68 + r] = a.z; VT[(i + 3) * 68 + r] = a.w;
  }
  __syncthreads();
#pragma unroll 2
  for (int i = 0; i < 128; i++) {
    const float2 xv = *(const float2*)&VT[i * 68 + r0];
    const float4 w0 = *(const float4*)&Wl[i * 132 + o0];
    const float4 w1 = *(const float4*)&Wl[i * 132 + o0 + 4];
    a0l.x += xv.x * w0.x; a0l.y += xv.x * w0.y; a0l.z += xv.x * w0.z; a0l.w += xv.x * w0.w;
    a0h.x += xv.x * w1.x; a0h.y += xv.x * w1.y; a0h.z += xv.x * w1.z; a0h.w += xv.x * w1.w;
    a1l.x += xv.y * w0.x; a1l.y += xv.y * w0.y; a1l.z += xv.y * w0.z; a1l.w += xv.y * w0.w;
    a1h.x += xv.y * w1.x; a1h.y += xv.y * w1.y; a1h.z += xv.y * w1.z; a1h.w += xv.y * w1.w;
  }
  *(float4*)&vx[((m0 + r0 + 0) << 7) + o0] = a0l;
  *(float4*)&vx[((m0 + r0 + 0) << 7) + o0 + 4] = a0h;
  *(float4*)&vx[((m0 + r0 + 1) << 7) + o0] = a1l;
  *(float4*)&vx[((m0 + r0 + 1) << 7) + o0 + 4] = a1h;
}

// ================= host =================
extern "C" void kernel_launch(void* const* d_in, const int* in_sizes, int n_in,
                              void* d_out, int out_size, void* d_ws, size_t ws_size,
                              hipStream_t stream) {
  (void)in_sizes; (void)n_in; (void)out_size;
  const float* u    = (const float*)d_in[0];
  const float* x0   = (const float*)d_in[1];
  const float* S    = (const float*)d_in[2];
  const float* Kraw = (const float*)d_in[3];
  float* out = (float*)d_out;
  float* yout = out;                       // y_seq: 32*4096*128
  float* vx   = out + 16777216LL;          // x_seq region; holds v_seq until k_phx
  float* ws = (float*)d_ws;
  if (ws_size < (size_t)(WS_FLOATS * 4)) return;

  float* MSQ0 = ws + O_MSQ0;  float* MSQ1 = ws + O_MSQ1;  float* PART = ws + O_PART;
  float* Z0 = ws + O_Z0;      float* Z1 = ws + O_Z1;      float* TN = ws + O_TN;
  float* WA = ws + O_WA;      float* WB = ws + O_WB;      float* WC = ws + O_WC;
  float* WD = ws + O_WD;      float* SINVT = ws + O_SINVT; float* V0 = ws + O_V0;
  float* PW = ws + O_PW;
  float* CONTRIB = ws + O_CONTRIB;  float* SC = ws + O_SC;
  float* SSUP = ws + O_SSUP;        float* SCHUNK = ws + O_SCHUNK;
  int* BAR = (int*)(ws + O_PART + 96);     // 32 ints in the unused PART tail

  // zero barrier counters (stream-ordered, graph-capturable)
  hipMemsetAsync((void*)BAR, 0, 32 * sizeof(int), stream);

  // prep: sigma chain + GJ (concurrent), then NS + WA powers (concurrent)
  k_prep1<<<65, 256, 0, stream>>>(Kraw, S, x0, MSQ0, MSQ1, PART, Z0,
                                  WA, WB, WC, WD, V0, BAR);
  k_prep2<<<32, 256, 0, stream>>>(S, Z0, Z1, TN, WA, PW, SINVT, BAR + 16, BAR + 24);

  float* P16 = PW + 49152;    // slot 3
  float* P256 = PW + 114688;  // slot 7

  const size_t scanLds = 135168;   // (16384 + 8192 + 256*36) * 4
  const size_t combLds = 69120;    // 17280 * 4
  const size_t gemmLds = 102400;   // (16896 + 8704) * 4

  // pass 1: chunk contributions
  k_scan<0><<<256, 512, scanLds, stream>>>(u, WA, WB, nullptr, nullptr, CONTRIB);
  // phase 2: hierarchical combine -> chunk-start states
  k_comb<<<512, 256, combLds, stream>>>(P16, nullptr, CONTRIB, nullptr, SC, 0);
  k_comb<<<32, 256, combLds, stream>>>(P256, V0, SC, SSUP, nullptr, 1);
  k_comb<<<512, 256, combLds, stream>>>(P16, SSUP, CONTRIB, SCHUNK, nullptr, 2);
  // pass 2: true states, stored to out (v-space)
  k_scan<1><<<256, 512, scanLds, stream>>>(u, WA, WB, SCHUNK, vx, nullptr);
  // outputs
  k_phy<<<2048, 512, gemmLds, stream>>>(vx, u, WC, WD, yout);
  k_phx<<<2048, 512, gemmLds, stream>>>(vx, SINVT);
}